// Round 5
// baseline (448.443 us; speedup 1.0000x reference)
//
#include <hip/hip_runtime.h>
#include <math.h>

#define BB 8
#define QQ 2048
#define GG 128
#define CC 512

// ---------------------------------------------------------------------------
// Kernel A (fused): final_cost[b][q][g] (output) + costT[b][g][q] (workspace,
// coalesced rows for the hungarian scans). Exact numpy f32 evaluation order.
// ---------------------------------------------------------------------------
__global__ __launch_bounds__(256) void cost_kernel(
    const float* __restrict__ sem,      // B,Q,C
    const float* __restrict__ center,   // B,Q,G
    const float* __restrict__ size_,    // B,Q,G
    const float* __restrict__ gious,    // B,Q,G
    const int*   __restrict__ labels,   // B,G
    float* __restrict__ final_cost,     // B,Q,G
    float* __restrict__ costT,          // B,G,Q (workspace) or nullptr
    int write_t)
{
#pragma clang fp contract(off)
    __shared__ int   lab[GG];
    __shared__ float tile[32][GG + 1];
    const int t  = threadIdx.x;
    const int b  = blockIdx.x >> 6;
    const int q0 = (blockIdx.x & 63) << 5;
    if (t < GG) lab[t] = labels[b * GG + t];
    __syncthreads();

    for (int k = 0; k < 16; ++k) {
        int lin = k * 256 + t;
        int qi  = lin >> 7;
        int g   = lin & 127;
        size_t bq  = (size_t)b * QQ + (q0 + qi);
        float x = sem[bq * CC + lab[g]];
        float p = 1.0f / (1.0f + expf(-x));
        float tt  = p - 1e-8f;
        float neg = (0.75f * (p * p)) * (-log1pf(-tt));
        float omp = 1.0f - p;
        float pos = (0.25f * (omp * omp)) * (-logf(p + 1e-8f));
        float diff = pos - neg;
        size_t idx = bq * GG + g;
        float c0 = (2.0f * diff) + (5.0f * center[idx]);
        float c1 = c0 + (1.0f * size_[idx]);
        float cost = c1 + (2.0f * (-gious[idx]));
        final_cost[idx] = cost;
        tile[qi][g] = cost;
    }
    if (!write_t) return;
    __syncthreads();
    for (int k = 0; k < 16; ++k) {
        int lin = k * 256 + t;
        int g   = lin >> 5;
        int qi  = lin & 31;
        costT[((size_t)b * GG + g) * QQ + (q0 + qi)] = tile[qi][g];
    }
}

// ---------------------------------------------------------------------------
// f64 (key,col) lexicographic min allreduce across 64 lanes, VALU-dominant:
// quad_perm xor1, xor2; row_ror:4, row_ror:8 (covers each 16-lane row);
// ds_swizzle xor16 (covers 32); __shfl_xor 32 (covers 64).
// Every level is min(x, perm(x)) over a bijection -> all lanes get the min.
// ---------------------------------------------------------------------------
__device__ __forceinline__ double i2d_(int lo, int hi) {
    union { double d; int i[2]; } u_; u_.i[0] = lo; u_.i[1] = hi; return u_.d;
}
__device__ __forceinline__ void d2i_(double d, int& lo, int& hi) {
    union { double d; int i[2]; } u_; u_.d = d; lo = u_.i[0]; hi = u_.i[1];
}
template<int CTRL>
__device__ __forceinline__ void red_lvl_dpp(double& key, int& col) {
    int lo, hi; d2i_(key, lo, hi);
    int olo = __builtin_amdgcn_update_dpp(0, lo,  CTRL, 0xF, 0xF, true);
    int ohi = __builtin_amdgcn_update_dpp(0, hi,  CTRL, 0xF, 0xF, true);
    int oc  = __builtin_amdgcn_update_dpp(0, col, CTRL, 0xF, 0xF, true);
    double ok = i2d_(olo, ohi);
    if (ok < key || (ok == key && oc < col)) { key = ok; col = oc; }
}
__device__ __forceinline__ void red_lvl_swz16(double& key, int& col) {
    int lo, hi; d2i_(key, lo, hi);
    int olo = __builtin_amdgcn_ds_swizzle(lo,  0x401F);
    int ohi = __builtin_amdgcn_ds_swizzle(hi,  0x401F);
    int oc  = __builtin_amdgcn_ds_swizzle(col, 0x401F);
    double ok = i2d_(olo, ohi);
    if (ok < key || (ok == key && oc < col)) { key = ok; col = oc; }
}

// ---------------------------------------------------------------------------
// Kernel B: reference's degenerate JV, single wave per batch, deferred updates.
// Per chain step (row i, current row i0):
//   key_c = ((double)C[i0][c] - u[i0]) - v[c] over non-used cols; argmin with
//   first-index ties; delta = key_min. Updates u[p0[c]] += delta, v[c] -= delta
//   for used cols + u[i] += delta are DEFERRED: within a chain the updated rows
//   are never re-read (i0 rows distinct) and updated cols are all used
//   (excluded), so logging (delta, col) per step and replaying chronologically
//   at chain end is bit-exact vs the reference's per-step f64 updates.
// A-part: untouched cols (v==0 exactly): f32 order == f64 key order (u bounded
// far below the 2^29 collapse threshold), tree-argmin over 32 cols/lane.
// B-part: touched cols in an S-list; first 512 slots register-resident
// (8 static slots/lane + used flags), LDS overflow beyond.
// ---------------------------------------------------------------------------
template<bool VEC>
__global__ __launch_bounds__(64) void hungarian_kernel(
    const float* __restrict__ costm,    // VEC: costT [b][g][q]; else final_cost [b][q][g]
    const int*   __restrict__ nactual,
    float* __restrict__ out_inds,
    float* __restrict__ out_mask)
{
    __shared__ double u_s[GG + 2];             // row potentials (1..128)
    __shared__ double Sv[QQ];                  // v per S-slot
    __shared__ unsigned short sIdx[QQ];        // col -> slot
    __shared__ unsigned short ScolL[QQ];       // slot -> col (overflow scans)
    __shared__ unsigned short p0[QQ];          // col -> row (0 = free)
    __shared__ unsigned int usedBits[QQ / 32]; // per-slot used (overflow path)
    __shared__ double dLog[GG];                // chain delta log
    __shared__ int    cLog[GG];                // chain col log

    const int b    = blockIdx.x;
    const int lane = threadIdx.x;              // 0..63
    int n = nactual[b];
    if (n < 0) n = 0;
    if (n > GG) n = GG;
    const float* cb = costm + (size_t)b * QQ * GG;
    const double DINF = __builtin_huge_val();
    const float  FINF = __builtin_huge_valf();

    for (int t = lane; t < QQ; t += 64) p0[t] = 0;
    for (int t = lane; t < GG + 2; t += 64) u_s[t] = 0.0;
    int Scol[8];
    #pragma unroll
    for (int k = 0; k < 8; ++k) Scol[k] = 0;
    unsigned excl = 0;                          // touched bits for my 32 A-cols
    int S_len = 0;
    __syncthreads();

    for (int i = 1; i <= n; ++i) {
        int usedR = 0;                          // used flags, my 8 reg slots
        usedBits[lane] = 0;                     // used bits, all slots (overflow)
        int K = 0;
        int i0 = i;
        double u_i0 = u_s[i];

        while (true) {
            const float* rowp = VEC ? (cb + (size_t)(i0 - 1) * QQ) : (cb + (i0 - 1));

            // ---- issue B-slot loads early (unconditional; predicate at use) ----
            float  bC[8];
            double sv[8];
            #pragma unroll
            for (int k = 0; k < 8; ++k) {
                int c = Scol[k];
                bC[k] = VEC ? rowp[c] : rowp[(size_t)c * GG];
                sv[k] = Sv[(k << 6) + lane];
            }

            // ---- A: load my 32 contiguous cols, tree argmin (f32, first-index ties) ----
            float lv[32];
            if (VEC) {
                const float4* rp4 = reinterpret_cast<const float4*>(rowp) + (lane << 3);
                #pragma unroll
                for (int k = 0; k < 8; ++k) {
                    float4 q4 = rp4[k];
                    lv[4 * k + 0] = q4.x; lv[4 * k + 1] = q4.y;
                    lv[4 * k + 2] = q4.z; lv[4 * k + 3] = q4.w;
                }
            } else {
                #pragma unroll
                for (int k = 0; k < 32; ++k)
                    lv[k] = rowp[(size_t)((lane << 5) + k) * GG];
            }
            #pragma unroll
            for (int k = 0; k < 32; ++k)
                if ((excl >> k) & 1u) lv[k] = FINF;

            const int cb0 = lane << 5;
            float tv8[16]; int tc8[16];
            #pragma unroll
            for (int k = 0; k < 16; ++k) {
                bool r = lv[2 * k + 1] < lv[2 * k];
                tv8[k] = r ? lv[2 * k + 1] : lv[2 * k];
                tc8[k] = cb0 + (r ? 2 * k + 1 : 2 * k);
            }
            float tv4[8]; int tc4[8];
            #pragma unroll
            for (int k = 0; k < 8; ++k) {
                bool r = tv8[2 * k + 1] < tv8[2 * k];
                tv4[k] = r ? tv8[2 * k + 1] : tv8[2 * k];
                tc4[k] = r ? tc8[2 * k + 1] : tc8[2 * k];
            }
            float tv2[4]; int tc2[4];
            #pragma unroll
            for (int k = 0; k < 4; ++k) {
                bool r = tv4[2 * k + 1] < tv4[2 * k];
                tv2[k] = r ? tv4[2 * k + 1] : tv4[2 * k];
                tc2[k] = r ? tc4[2 * k + 1] : tc4[2 * k];
            }
            float tv1[2]; int tc1[2];
            #pragma unroll
            for (int k = 0; k < 2; ++k) {
                bool r = tv2[2 * k + 1] < tv2[2 * k];
                tv1[k] = r ? tv2[2 * k + 1] : tv2[2 * k];
                tc1[k] = r ? tc2[2 * k + 1] : tc2[2 * k];
            }
            bool rA = tv1[1] < tv1[0];
            float vA = rA ? tv1[1] : tv1[0];
            int   cA = rA ? tc1[1] : tc1[0];

            double key = (vA < FINF) ? ((double)vA - u_i0) : DINF;
            int    col = cA;

            // ---- B: register slots (exact f64) ----
            #pragma unroll
            for (int k = 0; k < 8; ++k) {
                int t = (k << 6) + lane;
                bool valid = (t < S_len) && !((usedR >> k) & 1);
                double kb = ((double)bC[k] - u_i0) - sv[k];
                if (valid && (kb < key || (kb == key && Scol[k] < col))) {
                    key = kb; col = Scol[k];
                }
            }
            // ---- B: overflow slots (rare) ----
            if (S_len > 512) {
                for (int t = 512 + lane; t < S_len; t += 64) {
                    if (!((usedBits[t >> 5] >> (t & 31)) & 1u)) {
                        int c = ScolL[t];
                        float cf = VEC ? rowp[c] : rowp[(size_t)c * GG];
                        double kb = ((double)cf - u_i0) - Sv[t];
                        if (kb < key || (kb == key && c < col)) { key = kb; col = c; }
                    }
                }
            }

            // ---- 64-lane (key,col) min allreduce ----
            red_lvl_dpp<0xB1>(key, col);    // quad_perm xor1
            red_lvl_dpp<0x4E>(key, col);    // quad_perm xor2
            red_lvl_dpp<0x124>(key, col);   // row_ror:4
            red_lvl_dpp<0x128>(key, col);   // row_ror:8
            red_lvl_swz16(key, col);        // xor16
            {
                double ok = __shfl_xor(key, 32);
                int    oc = __shfl_xor(col, 32);
                if (ok < key || (ok == key && oc < col)) { key = ok; col = oc; }
            }
            const double delta = key;
            const int    dc    = col;
            const int    pr    = p0[dc];
            if (lane == 0) { cLog[K] = dc; dLog[K] = delta; }
            ++K;

            if (pr == 0) {
                // ---- augment + chronological replay of deferred updates ----
                if (lane == 0) p0[dc] = (unsigned short)i;
                __syncthreads();
                for (int m = lane; m < K - 1; m += 64) {
                    int c = cLog[m];
                    int slot = sIdx[c];
                    int r = p0[c];
                    double svv = Sv[slot], uu = u_s[r];
                    for (int t = m + 1; t < K; ++t) {
                        double d = dLog[t];
                        svv -= d; uu += d;
                    }
                    Sv[slot] = svv; u_s[r] = uu;
                }
                if (lane == 0) {
                    double uu = u_s[i];
                    for (int t = 0; t < K; ++t) uu += dLog[t];
                    u_s[i] = uu;
                }
                __syncthreads();
                break;
            }

            // ---- continue chain: mark used / append to S ----
            bool found = false;
            #pragma unroll
            for (int k = 0; k < 8; ++k) {
                int t = (k << 6) + lane;
                if (t < S_len && Scol[k] == dc) { usedR |= 1 << k; found = true; }
            }
            if (S_len > 512) {
                for (int t = 512 + lane; t < S_len; t += 64) {
                    if (ScolL[t] == dc) { usedBits[t >> 5] |= 1u << (t & 31); found = true; }
                }
            }
            if (!__any(found)) {
                int slot = S_len;
                if (lane == (slot & 63)) {
                    int kk = slot >> 6;
                    if (kk < 8) {
                        #pragma unroll
                        for (int k = 0; k < 8; ++k)
                            if (k == kk) { Scol[k] = dc; usedR |= 1 << k; }
                    } else {
                        usedBits[slot >> 5] |= 1u << (slot & 31);
                    }
                }
                if (lane == 0) {
                    Sv[slot] = 0.0;
                    sIdx[dc] = (unsigned short)slot;
                    ScolL[slot] = (unsigned short)dc;
                }
                if (lane == (dc >> 5)) excl |= 1u << (dc & 31);
                ++S_len;
            }
            i0 = pr;
            u_i0 = u_s[pr];          // prefetch next row potential
        }
    }

    for (int c = lane; c < QQ; c += 64) {
        int pr = p0[c];
        out_inds[(size_t)b * QQ + c] = (pr > 0) ? (float)(pr - 1) : 0.0f;
        out_mask[(size_t)b * QQ + c] = (pr > 0) ? 1.0f : 0.0f;
    }
}

extern "C" void kernel_launch(void* const* d_in, const int* in_sizes, int n_in,
                              void* d_out, int out_size, void* d_ws, size_t ws_size,
                              hipStream_t stream) {
    const float* sem     = (const float*)d_in[0];
    const float* center  = (const float*)d_in[1];
    const float* size_   = (const float*)d_in[2];
    const float* gious   = (const float*)d_in[3];
    const int*   labels  = (const int*)d_in[4];
    const int*   nactual = (const int*)d_in[5];

    float* out        = (float*)d_out;
    float* out_inds   = out;
    float* out_mask   = out + BB * QQ;
    float* final_cost = out + 2 * BB * QQ;

    const size_t t_bytes = (size_t)BB * GG * QQ * sizeof(float);
    const int use_t = (ws_size >= t_bytes) ? 1 : 0;
    float* costT = use_t ? (float*)d_ws : nullptr;

    cost_kernel<<<BB * 64, 256, 0, stream>>>(
        sem, center, size_, gious, labels, final_cost, costT, use_t);

    if (use_t) {
        hungarian_kernel<true><<<BB, 64, 0, stream>>>(costT, nactual, out_inds, out_mask);
    } else {
        hungarian_kernel<false><<<BB, 64, 0, stream>>>(final_cost, nactual, out_inds, out_mask);
    }
}

// Round 6
// 393.889 us; speedup vs baseline: 1.1385x; 1.1385x over previous
//
#include <hip/hip_runtime.h>
#include <math.h>

#define BB 8
#define QQ 2048
#define GG 128
#define CC 512
#define TK 32

// ---------------------------------------------------------------------------
// Kernel A (fused): final_cost[b][q][g] (output) + costT[b][g][q] (workspace,
// coalesced rows for hungarian fallback scans + topk build). Exact numpy f32
// evaluation order, contraction off.
// ---------------------------------------------------------------------------
__global__ __launch_bounds__(256) void cost_kernel(
    const float* __restrict__ sem,      // B,Q,C
    const float* __restrict__ center,   // B,Q,G
    const float* __restrict__ size_,    // B,Q,G
    const float* __restrict__ gious,    // B,Q,G
    const int*   __restrict__ labels,   // B,G
    float* __restrict__ final_cost,     // B,Q,G
    float* __restrict__ costT,          // B,G,Q (workspace) or nullptr
    int write_t)
{
#pragma clang fp contract(off)
    __shared__ int   lab[GG];
    __shared__ float tile[32][GG + 1];
    const int t  = threadIdx.x;
    const int b  = blockIdx.x >> 6;
    const int q0 = (blockIdx.x & 63) << 5;
    if (t < GG) lab[t] = labels[b * GG + t];
    __syncthreads();

    for (int k = 0; k < 16; ++k) {
        int lin = k * 256 + t;
        int qi  = lin >> 7;
        int g   = lin & 127;
        size_t bq  = (size_t)b * QQ + (q0 + qi);
        float x = sem[bq * CC + lab[g]];
        float p = 1.0f / (1.0f + expf(-x));
        float tt  = p - 1e-8f;
        float neg = (0.75f * (p * p)) * (-log1pf(-tt));
        float omp = 1.0f - p;
        float pos = (0.25f * (omp * omp)) * (-logf(p + 1e-8f));
        float diff = pos - neg;
        size_t idx = bq * GG + g;
        float c0 = (2.0f * diff) + (5.0f * center[idx]);
        float c1 = c0 + (1.0f * size_[idx]);
        float cost = c1 + (2.0f * (-gious[idx]));
        final_cost[idx] = cost;
        tile[qi][g] = cost;
    }
    if (!write_t) return;
    __syncthreads();
    for (int k = 0; k < 16; ++k) {
        int lin = k * 256 + t;
        int g   = lin >> 5;
        int qi  = lin & 31;
        costT[((size_t)b * GG + g) * QQ + (q0 + qi)] = tile[qi][g];
    }
}

// ---------------------------------------------------------------------------
// Cross-lane lex-(key,col) min allreduce helpers (verified on HW in R5):
// quad_perm xor1 (0xB1), xor2 (0x4E); row_ror:4 (0x124); row_ror:8 (0x128);
// ds_swizzle xor16; __shfl_xor 32. Each level is min over a lane bijection.
// ---------------------------------------------------------------------------
__device__ __forceinline__ double i2d_(int lo, int hi) {
    union { double d; int i[2]; } u_; u_.i[0] = lo; u_.i[1] = hi; return u_.d;
}
__device__ __forceinline__ void d2i_(double d, int& lo, int& hi) {
    union { double d; int i[2]; } u_; u_.d = d; lo = u_.i[0]; hi = u_.i[1];
}
template<int CTRL>
__device__ __forceinline__ void red64_dpp(double& key, int& col) {
    int lo, hi; d2i_(key, lo, hi);
    int olo = __builtin_amdgcn_update_dpp(0, lo,  CTRL, 0xF, 0xF, true);
    int ohi = __builtin_amdgcn_update_dpp(0, hi,  CTRL, 0xF, 0xF, true);
    int oc  = __builtin_amdgcn_update_dpp(0, col, CTRL, 0xF, 0xF, true);
    double ok = i2d_(olo, ohi);
    if (ok < key || (ok == key && oc < col)) { key = ok; col = oc; }
}
__device__ __forceinline__ void red64_swz16(double& key, int& col) {
    int lo, hi; d2i_(key, lo, hi);
    int olo = __builtin_amdgcn_ds_swizzle(lo,  0x401F);
    int ohi = __builtin_amdgcn_ds_swizzle(hi,  0x401F);
    int oc  = __builtin_amdgcn_ds_swizzle(col, 0x401F);
    double ok = i2d_(olo, ohi);
    if (ok < key || (ok == key && oc < col)) { key = ok; col = oc; }
}
__device__ __forceinline__ void reduce64(double& key, int& col) {
    red64_dpp<0xB1>(key, col);
    red64_dpp<0x4E>(key, col);
    red64_dpp<0x124>(key, col);
    red64_dpp<0x128>(key, col);
    red64_swz16(key, col);
    double ok = __shfl_xor(key, 32);
    int    oc = __shfl_xor(col, 32);
    if (ok < key || (ok == key && oc < col)) { key = ok; col = oc; }
}
template<int CTRL>
__device__ __forceinline__ void red32_dpp(float& v, int& c) {
    int ov_ = __builtin_amdgcn_update_dpp(0, __float_as_int(v), CTRL, 0xF, 0xF, true);
    int oc  = __builtin_amdgcn_update_dpp(0, c, CTRL, 0xF, 0xF, true);
    float ov = __int_as_float(ov_);
    if (ov < v || (ov == v && oc < c)) { v = ov; c = oc; }
}
__device__ __forceinline__ void reduce32(float& v, int& c) {
    red32_dpp<0xB1>(v, c);
    red32_dpp<0x4E>(v, c);
    red32_dpp<0x124>(v, c);
    red32_dpp<0x128>(v, c);
    {
        float ov = __int_as_float(__builtin_amdgcn_ds_swizzle(__float_as_int(v), 0x401F));
        int   oc = __builtin_amdgcn_ds_swizzle(c, 0x401F);
        if (ov < v || (ov == v && oc < c)) { v = ov; c = oc; }
    }
    {
        float ov = __shfl_xor(v, 32);
        int   oc = __shfl_xor(c, 32);
        if (ov < v || (ov == v && oc < c)) { v = ov; c = oc; }
    }
}

// ---------------------------------------------------------------------------
// Kernel T: per row (b,g) of costT, extract the 32 lex-(val,col)-smallest
// entries by iterated argmin. One wave per row, 1024 independent blocks.
// Per-lane cols ascending in register index -> strict < keeps smallest col.
// ---------------------------------------------------------------------------
__global__ __launch_bounds__(64) void topk_kernel(
    const float* __restrict__ costT,
    float* __restrict__ topv, int* __restrict__ topc)
{
    const int row  = blockIdx.x;            // b*GG + g
    const int lane = threadIdx.x;
    const float FINF = __builtin_huge_valf();
    const float4* rp4 = reinterpret_cast<const float4*>(costT + (size_t)row * QQ);

    float lv[32]; int lc[32];
    #pragma unroll
    for (int k = 0; k < 8; ++k) {           // coalesced: lanes consecutive float4
        float4 q4 = rp4[k * 64 + lane];
        int c0 = k * 256 + lane * 4;
        lv[4*k+0] = q4.x; lc[4*k+0] = c0 + 0;
        lv[4*k+1] = q4.y; lc[4*k+1] = c0 + 1;
        lv[4*k+2] = q4.z; lc[4*k+2] = c0 + 2;
        lv[4*k+3] = q4.w; lc[4*k+3] = c0 + 3;
    }
    for (int it = 0; it < TK; ++it) {
        float tv16[16]; int tc16[16];
        #pragma unroll
        for (int k = 0; k < 16; ++k) {
            bool r = lv[2*k+1] < lv[2*k];
            tv16[k] = r ? lv[2*k+1] : lv[2*k];
            tc16[k] = r ? lc[2*k+1] : lc[2*k];
        }
        float tv8[8]; int tc8[8];
        #pragma unroll
        for (int k = 0; k < 8; ++k) {
            bool r = tv16[2*k+1] < tv16[2*k];
            tv8[k] = r ? tv16[2*k+1] : tv16[2*k];
            tc8[k] = r ? tc16[2*k+1] : tc16[2*k];
        }
        float tv4[4]; int tc4[4];
        #pragma unroll
        for (int k = 0; k < 4; ++k) {
            bool r = tv8[2*k+1] < tv8[2*k];
            tv4[k] = r ? tv8[2*k+1] : tv8[2*k];
            tc4[k] = r ? tc8[2*k+1] : tc8[2*k];
        }
        float tv2[2]; int tc2[2];
        #pragma unroll
        for (int k = 0; k < 2; ++k) {
            bool r = tv4[2*k+1] < tv4[2*k];
            tv2[k] = r ? tv4[2*k+1] : tv4[2*k];
            tc2[k] = r ? tc4[2*k+1] : tc4[2*k];
        }
        bool rr = tv2[1] < tv2[0];
        float v = rr ? tv2[1] : tv2[0];
        int   c = rr ? tc2[1] : tc2[0];
        reduce32(v, c);                     // lex min across 64 lanes
        if (lane == 0) {
            topv[(size_t)row * TK + it] = v;
            topc[(size_t)row * TK + it] = c;
        }
        #pragma unroll
        for (int k = 0; k < 32; ++k)
            if (lc[k] == c) lv[k] = FINF;   // invalidate extracted entry
    }
}

// ---------------------------------------------------------------------------
// Kernel B: reference's degenerate JV, single wave per batch.
// Per chain step (row i, current row i0): key_c = ((double)C[i0][c]-u[i0])-v[c]
// over non-used cols; argmin, first-index ties; delta = key_min. u/v updates
// deferred to chain end and replayed chronologically (bit-exact: chain rows
// are never re-scanned, used cols are excluded).
// A-part (untouched cols, v==0 exactly, f32 order == f64 key order): first
// untouched entry of the row's precomputed sorted top-32 list (exact: any col
// outside the list is lex-(val,col) greater than every list entry). Fallback
// to full row scan when the list is exhausted (rare).
// B-part (touched cols): LDS S-list, predicated gathers, exact f64 v.
// ---------------------------------------------------------------------------
template<bool VEC>
__global__ __launch_bounds__(64) void hungarian_kernel(
    const float* __restrict__ costm,    // VEC: costT [b][g][q]; else final_cost [b][q][g]
    const int*   __restrict__ nactual,
    float* __restrict__ out_inds,
    float* __restrict__ out_mask,
    const float* __restrict__ topv,     // [b*GG + g][TK] or nullptr
    const int*   __restrict__ topc)
{
    __shared__ float          Ltv[GG][TK];     // sorted top vals
    __shared__ unsigned short Ltc[GG][TK];     // sorted top cols
    __shared__ double u_s[GG + 2];             // row potentials (1..128)
    __shared__ double Sv[QQ];                  // v per S-slot (f64 exact)
    __shared__ unsigned short ScolL[QQ];       // slot -> col
    __shared__ unsigned short sIdx[QQ];        // col -> slot
    __shared__ unsigned short p0[QQ];          // col -> row (0 = free)
    __shared__ unsigned int tb[QQ / 32];       // touched bitmap (== in S)
    __shared__ unsigned int usedBits[QQ / 32]; // per-SLOT used bits
    __shared__ double dLog[GG];                // chain delta log
    __shared__ int    cLog[GG];                // chain col log

    const int b    = blockIdx.x;
    const int lane = threadIdx.x;              // 0..63
    int n = nactual[b];
    if (n < 0) n = 0;
    if (n > GG) n = GG;
    const float* cb = costm + (size_t)b * QQ * GG;
    const double DINF = __builtin_huge_val();
    const float  FINF = __builtin_huge_valf();
    const bool hasTopk = (topv != nullptr);

    for (int t = lane; t < QQ; t += 64) p0[t] = 0;
    for (int t = lane; t < GG + 2; t += 64) u_s[t] = 0.0;
    tb[lane] = 0;
    if (hasTopk) {
        for (int t = lane; t < GG * TK; t += 64) {
            Ltv[t / TK][t % TK] = topv[(size_t)b * GG * TK + t];
            Ltc[t / TK][t % TK] = (unsigned short)topc[(size_t)b * GG * TK + t];
        }
    }
    unsigned excl = 0;                          // touched bits for my 32 A-cols
    int S_len = 0;
    __syncthreads();

    for (int i = 1; i <= n; ++i) {
        usedBits[lane] = 0;
        int K = 0;
        int i0 = i;
        double u_i0 = u_s[i];

        while (true) {
            const float* rowp = VEC ? (cb + (size_t)(i0 - 1) * QQ) : (cb + (i0 - 1));

            // ---- B: predicated gathers over S-slots (issue first) ----
            double kc = DINF; int cc = 1 << 30;
            for (int t = lane; t < S_len; t += 64) {
                int c = ScolL[t];
                float cf = VEC ? rowp[c] : rowp[(size_t)c * GG];
                bool us = (usedBits[t >> 5] >> (t & 31)) & 1u;
                double kb = ((double)cf - u_i0) - Sv[t];
                if (!us && (kb < kc || (kb == kc && c < cc))) { kc = kb; cc = c; }
            }

            // ---- A: first untouched entry of row i0's sorted top-32 ----
            bool listHit = false; float vA = FINF; int cA = 0;
            if (hasTopk) {
                float av = FINF; int ac = 0; bool avalid = false;
                if (lane < TK) {
                    av = Ltv[i0 - 1][lane];
                    ac = Ltc[i0 - 1][lane];
                    avalid = ((tb[ac >> 5] >> (ac & 31)) & 1u) == 0;
                }
                unsigned long long mm = __ballot(avalid);
                if (mm != 0ull) {
                    int fl = __ffsll(mm) - 1;
                    vA = __shfl(av, fl);
                    cA = __shfl(ac, fl);
                    listHit = true;
                }
            }
            if (!listHit) {
                // ---- fallback: full row scan (f32, per-lane ascending cols) ----
                float lv[32];
                if (VEC) {
                    const float4* rp4 = reinterpret_cast<const float4*>(rowp) + (lane << 3);
                    #pragma unroll
                    for (int k = 0; k < 8; ++k) {
                        float4 q4 = rp4[k];
                        lv[4*k+0] = q4.x; lv[4*k+1] = q4.y;
                        lv[4*k+2] = q4.z; lv[4*k+3] = q4.w;
                    }
                } else {
                    #pragma unroll
                    for (int k = 0; k < 32; ++k)
                        lv[k] = rowp[(size_t)((lane << 5) + k) * GG];
                }
                #pragma unroll
                for (int k = 0; k < 32; ++k)
                    if ((excl >> k) & 1u) lv[k] = FINF;
                float tv16[16]; int tc16[16];
                const int cb0 = lane << 5;
                #pragma unroll
                for (int k = 0; k < 16; ++k) {
                    bool r = lv[2*k+1] < lv[2*k];
                    tv16[k] = r ? lv[2*k+1] : lv[2*k];
                    tc16[k] = cb0 + (r ? 2*k+1 : 2*k);
                }
                float tv8[8]; int tc8[8];
                #pragma unroll
                for (int k = 0; k < 8; ++k) {
                    bool r = tv16[2*k+1] < tv16[2*k];
                    tv8[k] = r ? tv16[2*k+1] : tv16[2*k];
                    tc8[k] = r ? tc16[2*k+1] : tc16[2*k];
                }
                float tv4[4]; int tc4[4];
                #pragma unroll
                for (int k = 0; k < 4; ++k) {
                    bool r = tv8[2*k+1] < tv8[2*k];
                    tv4[k] = r ? tv8[2*k+1] : tv8[2*k];
                    tc4[k] = r ? tc8[2*k+1] : tc8[2*k];
                }
                float tv2[2]; int tc2[2];
                #pragma unroll
                for (int k = 0; k < 2; ++k) {
                    bool r = tv4[2*k+1] < tv4[2*k];
                    tv2[k] = r ? tv4[2*k+1] : tv4[2*k];
                    tc2[k] = r ? tc4[2*k+1] : tc4[2*k];
                }
                bool rr = tv2[1] < tv2[0];
                float fv = rr ? tv2[1] : tv2[0];
                int   fc = rr ? tc2[1] : tc2[0];
                if (fv < FINF) {
                    double ka = (double)fv - u_i0;   // v==0 exactly for A-cols
                    if (ka < kc || (ka == kc && fc < cc)) { kc = ka; cc = fc; }
                }
            }

            // ---- combine & reduce ----
            double delta; int dc;
            const bool needReduce = (S_len > 0) || !listHit;
            if (needReduce) {
                reduce64(kc, cc);
                if (listHit) {
                    double ka = (double)vA - u_i0;
                    if (kc < ka || (kc == ka && cc < cA)) { delta = kc; dc = cc; }
                    else                                  { delta = ka; dc = cA; }
                } else { delta = kc; dc = cc; }
            } else { delta = (double)vA - u_i0; dc = cA; }

            const int pr = p0[dc];
            if (lane == 0) { cLog[K] = dc; dLog[K] = delta; }
            ++K;

            if (pr == 0) {
                // ---- augment + chronological replay of deferred updates ----
                if (lane == 0) p0[dc] = (unsigned short)i;
                __syncthreads();
                for (int m = lane; m < K - 1; m += 64) {
                    int c = cLog[m];
                    int slot = sIdx[c];
                    int r = p0[c];
                    double svv = Sv[slot], uu = u_s[r];
                    for (int t = m + 1; t < K; ++t) {
                        double d = dLog[t];
                        svv -= d; uu += d;
                    }
                    Sv[slot] = svv; u_s[r] = uu;
                }
                if (lane == 0) {
                    double uu = u_s[i];
                    for (int t = 0; t < K; ++t) uu += dLog[t];
                    u_s[i] = uu;
                }
                __syncthreads();
                break;
            }

            // ---- continue chain: append to S if new, mark slot used ----
            const bool inS = (tb[dc >> 5] >> (dc & 31)) & 1u;
            if (!inS) {
                int slot = S_len;
                if (lane == 0) {
                    ScolL[slot] = (unsigned short)dc;
                    Sv[slot]    = 0.0;
                    sIdx[dc]    = (unsigned short)slot;
                    tb[dc >> 5]       |= 1u << (dc & 31);
                    usedBits[slot >> 5] |= 1u << (slot & 31);
                }
                if (lane == (dc >> 5)) excl |= 1u << (dc & 31);
                ++S_len;
            } else {
                int slot = sIdx[dc];
                if (lane == 0) usedBits[slot >> 5] |= 1u << (slot & 31);
            }
            i0 = pr;
            u_i0 = u_s[pr];
        }
    }

    for (int c = lane; c < QQ; c += 64) {
        int pr = p0[c];
        out_inds[(size_t)b * QQ + c] = (pr > 0) ? (float)(pr - 1) : 0.0f;
        out_mask[(size_t)b * QQ + c] = (pr > 0) ? 1.0f : 0.0f;
    }
}

extern "C" void kernel_launch(void* const* d_in, const int* in_sizes, int n_in,
                              void* d_out, int out_size, void* d_ws, size_t ws_size,
                              hipStream_t stream) {
    const float* sem     = (const float*)d_in[0];
    const float* center  = (const float*)d_in[1];
    const float* size_   = (const float*)d_in[2];
    const float* gious   = (const float*)d_in[3];
    const int*   labels  = (const int*)d_in[4];
    const int*   nactual = (const int*)d_in[5];

    float* out        = (float*)d_out;
    float* out_inds   = out;
    float* out_mask   = out + BB * QQ;
    float* final_cost = out + 2 * BB * QQ;

    const size_t t_bytes = (size_t)BB * GG * QQ * sizeof(float);                 // 8 MB
    const size_t k_bytes = (size_t)BB * GG * TK * (sizeof(float) + sizeof(int)); // 256 KB
    const int use_t = (ws_size >= t_bytes) ? 1 : 0;
    const int use_k = (ws_size >= t_bytes + k_bytes) ? 1 : 0;
    float* costT = use_t ? (float*)d_ws : nullptr;
    float* topv  = (float*)((char*)d_ws + t_bytes);
    int*   topc  = (int*)((char*)d_ws + t_bytes + (size_t)BB * GG * TK * sizeof(float));

    cost_kernel<<<BB * 64, 256, 0, stream>>>(
        sem, center, size_, gious, labels, final_cost, costT, use_t);

    if (use_t) {
        if (use_k) topk_kernel<<<BB * GG, 64, 0, stream>>>(costT, topv, topc);
        hungarian_kernel<true><<<BB, 64, 0, stream>>>(
            costT, nactual, out_inds, out_mask,
            use_k ? topv : nullptr, use_k ? topc : nullptr);
    } else {
        hungarian_kernel<false><<<BB, 64, 0, stream>>>(
            final_cost, nactual, out_inds, out_mask, nullptr, nullptr);
    }
}

// Round 7
// 270.351 us; speedup vs baseline: 1.6587x; 1.4570x over previous
//
#include <hip/hip_runtime.h>
#include <math.h>

#define BB 8
#define QQ 2048
#define GG 128
#define CC 512
#define TK 32
#define CAND_CAP 512

// ---------------------------------------------------------------------------
// Kernel A (fused): final_cost[b][q][g] (output) + costT[b][g][q] (workspace,
// coalesced rows for hungarian fallback scans + topk build). Exact numpy f32
// evaluation order, contraction off.
// ---------------------------------------------------------------------------
__global__ __launch_bounds__(256) void cost_kernel(
    const float* __restrict__ sem,      // B,Q,C
    const float* __restrict__ center,   // B,Q,G
    const float* __restrict__ size_,    // B,Q,G
    const float* __restrict__ gious,    // B,Q,G
    const int*   __restrict__ labels,   // B,G
    float* __restrict__ final_cost,     // B,Q,G
    float* __restrict__ costT,          // B,G,Q (workspace) or nullptr
    int write_t)
{
#pragma clang fp contract(off)
    __shared__ int   lab[GG];
    __shared__ float tile[32][GG + 1];
    const int t  = threadIdx.x;
    const int b  = blockIdx.x >> 6;
    const int q0 = (blockIdx.x & 63) << 5;
    if (t < GG) lab[t] = labels[b * GG + t];
    __syncthreads();

    for (int k = 0; k < 16; ++k) {
        int lin = k * 256 + t;
        int qi  = lin >> 7;
        int g   = lin & 127;
        size_t bq  = (size_t)b * QQ + (q0 + qi);
        float x = sem[bq * CC + lab[g]];
        float p = 1.0f / (1.0f + expf(-x));
        float tt  = p - 1e-8f;
        float neg = (0.75f * (p * p)) * (-log1pf(-tt));
        float omp = 1.0f - p;
        float pos = (0.25f * (omp * omp)) * (-logf(p + 1e-8f));
        float diff = pos - neg;
        size_t idx = bq * GG + g;
        float c0 = (2.0f * diff) + (5.0f * center[idx]);
        float c1 = c0 + (1.0f * size_[idx]);
        float cost = c1 + (2.0f * (-gious[idx]));
        final_cost[idx] = cost;
        tile[qi][g] = cost;
    }
    if (!write_t) return;
    __syncthreads();
    for (int k = 0; k < 16; ++k) {
        int lin = k * 256 + t;
        int g   = lin >> 5;
        int qi  = lin & 31;
        costT[((size_t)b * GG + g) * QQ + (q0 + qi)] = tile[qi][g];
    }
}

// ---------------------------------------------------------------------------
// Cross-lane lex-(key,col) f64 min allreduce (verified on HW in R5/R6).
// ---------------------------------------------------------------------------
__device__ __forceinline__ double i2d_(int lo, int hi) {
    union { double d; int i[2]; } u_; u_.i[0] = lo; u_.i[1] = hi; return u_.d;
}
__device__ __forceinline__ void d2i_(double d, int& lo, int& hi) {
    union { double d; int i[2]; } u_; u_.d = d; lo = u_.i[0]; hi = u_.i[1];
}
template<int CTRL>
__device__ __forceinline__ void red64_dpp(double& key, int& col) {
    int lo, hi; d2i_(key, lo, hi);
    int olo = __builtin_amdgcn_update_dpp(0, lo,  CTRL, 0xF, 0xF, true);
    int ohi = __builtin_amdgcn_update_dpp(0, hi,  CTRL, 0xF, 0xF, true);
    int oc  = __builtin_amdgcn_update_dpp(0, col, CTRL, 0xF, 0xF, true);
    double ok = i2d_(olo, ohi);
    if (ok < key || (ok == key && oc < col)) { key = ok; col = oc; }
}
__device__ __forceinline__ void red64_swz16(double& key, int& col) {
    int lo, hi; d2i_(key, lo, hi);
    int olo = __builtin_amdgcn_ds_swizzle(lo,  0x401F);
    int ohi = __builtin_amdgcn_ds_swizzle(hi,  0x401F);
    int oc  = __builtin_amdgcn_ds_swizzle(col, 0x401F);
    double ok = i2d_(olo, ohi);
    if (ok < key || (ok == key && oc < col)) { key = ok; col = oc; }
}
__device__ __forceinline__ void reduce64(double& key, int& col) {
    red64_dpp<0xB1>(key, col);
    red64_dpp<0x4E>(key, col);
    red64_dpp<0x124>(key, col);
    red64_dpp<0x128>(key, col);
    red64_swz16(key, col);
    double ok = __shfl_xor(key, 32);
    int    oc = __shfl_xor(col, 32);
    if (ok < key || (ok == key && oc < col)) { key = ok; col = oc; }
}

// ---------------------------------------------------------------------------
// Kernel T (parallel radix-select): per row (b,g) of costT, the 32
// lex-(val,col)-smallest entries, sorted. 256 threads/row, no serial
// extraction. Keys: monotone u32 transform of f32 (with -0.0 -> +0.0).
// Two 8-bit histogram levels give the exact top-16-bit prefix P16 of the
// 32nd-smallest key; candidates {key>>16 <= P16} provably contain the
// top-32 multiset (count(key16<P16) < 32; 32nd key has key16==P16).
// Candidates ranked by counting u64 (key,col) compares; ranks 0..31 written.
// ---------------------------------------------------------------------------
__global__ __launch_bounds__(256) void topk_kernel(
    const float* __restrict__ costT,
    float* __restrict__ topv, int* __restrict__ topc)
{
    __shared__ unsigned int hist[256];
    __shared__ unsigned int cum[256];
    __shared__ unsigned long long cand[CAND_CAP];
    __shared__ int candN;
    __shared__ unsigned int s_selB, s_base;

    const int row = blockIdx.x;            // b*GG + g
    const int t   = threadIdx.x;
    const float* rp = costT + (size_t)row * QQ;

    // 8 values per thread, cols t*8 .. t*8+7 (two coalesced float4)
    float4 f0 = reinterpret_cast<const float4*>(rp)[t * 2];
    float4 f1 = reinterpret_cast<const float4*>(rp)[t * 2 + 1];
    float v[8] = {f0.x, f0.y, f0.z, f0.w, f1.x, f1.y, f1.z, f1.w};
    unsigned key[8];
    #pragma unroll
    for (int k = 0; k < 8; ++k) {
        unsigned u = __float_as_uint(v[k]);
        if (v[k] == 0.0f) u = 0u;                      // -0.0 == +0.0
        key[k] = (u >> 31) ? ~u : (u | 0x80000000u);   // monotone transform
    }

    unsigned need = TK;
    unsigned prefix = 0;

    // ---- level 0: bits 31..24 ----
    hist[t] = 0; __syncthreads();
    #pragma unroll
    for (int k = 0; k < 8; ++k) atomicAdd(&hist[key[k] >> 24], 1u);
    __syncthreads();
    if (t < 64) {                                      // wave-0 scan of 256 bins
        unsigned h0 = hist[4*t], h1 = hist[4*t+1], h2 = hist[4*t+2], h3 = hist[4*t+3];
        unsigned s0 = h0, s1 = s0 + h1, s2 = s1 + h2, s3 = s2 + h3;
        unsigned acc = s3;
        #pragma unroll
        for (int off = 1; off < 64; off <<= 1) {
            unsigned x = __shfl_up(acc, off);
            if (t >= off) acc += x;
        }
        unsigned excl = acc - s3;
        cum[4*t] = excl + s0; cum[4*t+1] = excl + s1;
        cum[4*t+2] = excl + s2; cum[4*t+3] = excl + s3;
    }
    __syncthreads();
    if (cum[t] >= need && (t == 0 || cum[t-1] < need)) {
        s_selB = (unsigned)t; s_base = cum[t] - hist[t];
    }
    __syncthreads();
    prefix = s_selB << 24;
    need  -= s_base;
    __syncthreads();                                   // before hist reuse

    // ---- level 1: bits 23..16 among keys with top byte == prefix>>24 ----
    hist[t] = 0; __syncthreads();
    #pragma unroll
    for (int k = 0; k < 8; ++k)
        if ((key[k] >> 24) == (prefix >> 24))
            atomicAdd(&hist[(key[k] >> 16) & 0xFFu], 1u);
    __syncthreads();
    if (t < 64) {
        unsigned h0 = hist[4*t], h1 = hist[4*t+1], h2 = hist[4*t+2], h3 = hist[4*t+3];
        unsigned s0 = h0, s1 = s0 + h1, s2 = s1 + h2, s3 = s2 + h3;
        unsigned acc = s3;
        #pragma unroll
        for (int off = 1; off < 64; off <<= 1) {
            unsigned x = __shfl_up(acc, off);
            if (t >= off) acc += x;
        }
        unsigned excl = acc - s3;
        cum[4*t] = excl + s0; cum[4*t+1] = excl + s1;
        cum[4*t+2] = excl + s2; cum[4*t+3] = excl + s3;
    }
    __syncthreads();
    if (cum[t] >= need && (t == 0 || cum[t-1] < need)) {
        s_selB = (unsigned)t;
    }
    if (t == 0) candN = 0;
    __syncthreads();
    prefix |= s_selB << 16;
    const unsigned P16 = prefix >> 16;
    __syncthreads();

    // ---- collect candidates {key16 <= P16} ----
    #pragma unroll
    for (int k = 0; k < 8; ++k) {
        if ((key[k] >> 16) <= P16) {
            int idx = atomicAdd(&candN, 1);
            if (idx < CAND_CAP)
                cand[idx] = ((unsigned long long)key[k] << 32) | (unsigned)(t * 8 + k);
        }
    }
    __syncthreads();
    int N = candN; if (N > CAND_CAP) N = CAND_CAP;

    // ---- rank by counting (u64 lex (key,col); cols distinct -> unique ranks)
    if (t < N) {
        unsigned long long me = cand[t];
        int r = 0;
        for (int j = 0; j < N; ++j) r += (cand[j] < me) ? 1 : 0;
        if (r < TK) {
            unsigned kk = (unsigned)(me >> 32);
            unsigned uu = (kk >> 31) ? (kk & 0x7FFFFFFFu) : ~kk;  // inverse transform
            topv[(size_t)row * TK + r] = __uint_as_float(uu);
            topc[(size_t)row * TK + r] = (int)(me & 0xFFFFFFFFull);
        }
    }
}

// ---------------------------------------------------------------------------
// Kernel B: reference's degenerate JV, single wave per batch (verified R6,
// unchanged). Deferred u/v updates, sorted top-32 A-list, LDS S-list B-part.
// ---------------------------------------------------------------------------
template<bool VEC>
__global__ __launch_bounds__(64) void hungarian_kernel(
    const float* __restrict__ costm,    // VEC: costT [b][g][q]; else final_cost [b][q][g]
    const int*   __restrict__ nactual,
    float* __restrict__ out_inds,
    float* __restrict__ out_mask,
    const float* __restrict__ topv,     // [b*GG + g][TK] or nullptr
    const int*   __restrict__ topc)
{
    __shared__ float          Ltv[GG][TK];     // sorted top vals
    __shared__ unsigned short Ltc[GG][TK];     // sorted top cols
    __shared__ double u_s[GG + 2];             // row potentials (1..128)
    __shared__ double Sv[QQ];                  // v per S-slot (f64 exact)
    __shared__ unsigned short ScolL[QQ];       // slot -> col
    __shared__ unsigned short sIdx[QQ];        // col -> slot
    __shared__ unsigned short p0[QQ];          // col -> row (0 = free)
    __shared__ unsigned int tb[QQ / 32];       // touched bitmap (== in S)
    __shared__ unsigned int usedBits[QQ / 32]; // per-SLOT used bits
    __shared__ double dLog[GG];                // chain delta log
    __shared__ int    cLog[GG];                // chain col log

    const int b    = blockIdx.x;
    const int lane = threadIdx.x;              // 0..63
    int n = nactual[b];
    if (n < 0) n = 0;
    if (n > GG) n = GG;
    const float* cb = costm + (size_t)b * QQ * GG;
    const double DINF = __builtin_huge_val();
    const float  FINF = __builtin_huge_valf();
    const bool hasTopk = (topv != nullptr);

    for (int t = lane; t < QQ; t += 64) p0[t] = 0;
    for (int t = lane; t < GG + 2; t += 64) u_s[t] = 0.0;
    tb[lane] = 0;
    if (hasTopk) {
        for (int t = lane; t < GG * TK; t += 64) {
            Ltv[t / TK][t % TK] = topv[(size_t)b * GG * TK + t];
            Ltc[t / TK][t % TK] = (unsigned short)topc[(size_t)b * GG * TK + t];
        }
    }
    unsigned excl = 0;                          // touched bits for my 32 A-cols
    int S_len = 0;
    __syncthreads();

    for (int i = 1; i <= n; ++i) {
        usedBits[lane] = 0;
        int K = 0;
        int i0 = i;
        double u_i0 = u_s[i];

        while (true) {
            const float* rowp = VEC ? (cb + (size_t)(i0 - 1) * QQ) : (cb + (i0 - 1));

            // ---- B: predicated gathers over S-slots (issue first) ----
            double kc = DINF; int cc = 1 << 30;
            for (int t = lane; t < S_len; t += 64) {
                int c = ScolL[t];
                float cf = VEC ? rowp[c] : rowp[(size_t)c * GG];
                bool us = (usedBits[t >> 5] >> (t & 31)) & 1u;
                double kb = ((double)cf - u_i0) - Sv[t];
                if (!us && (kb < kc || (kb == kc && c < cc))) { kc = kb; cc = c; }
            }

            // ---- A: first untouched entry of row i0's sorted top-32 ----
            bool listHit = false; float vA = FINF; int cA = 0;
            if (hasTopk) {
                float av = FINF; int ac = 0; bool avalid = false;
                if (lane < TK) {
                    av = Ltv[i0 - 1][lane];
                    ac = Ltc[i0 - 1][lane];
                    avalid = ((tb[ac >> 5] >> (ac & 31)) & 1u) == 0;
                }
                unsigned long long mm = __ballot(avalid);
                if (mm != 0ull) {
                    int fl = __ffsll(mm) - 1;
                    vA = __shfl(av, fl);
                    cA = __shfl(ac, fl);
                    listHit = true;
                }
            }
            if (!listHit) {
                // ---- fallback: full row scan (f32, per-lane ascending cols) ----
                float lv[32];
                if (VEC) {
                    const float4* rp4 = reinterpret_cast<const float4*>(rowp) + (lane << 3);
                    #pragma unroll
                    for (int k = 0; k < 8; ++k) {
                        float4 q4 = rp4[k];
                        lv[4*k+0] = q4.x; lv[4*k+1] = q4.y;
                        lv[4*k+2] = q4.z; lv[4*k+3] = q4.w;
                    }
                } else {
                    #pragma unroll
                    for (int k = 0; k < 32; ++k)
                        lv[k] = rowp[(size_t)((lane << 5) + k) * GG];
                }
                #pragma unroll
                for (int k = 0; k < 32; ++k)
                    if ((excl >> k) & 1u) lv[k] = FINF;
                float tv16[16]; int tc16[16];
                const int cb0 = lane << 5;
                #pragma unroll
                for (int k = 0; k < 16; ++k) {
                    bool r = lv[2*k+1] < lv[2*k];
                    tv16[k] = r ? lv[2*k+1] : lv[2*k];
                    tc16[k] = cb0 + (r ? 2*k+1 : 2*k);
                }
                float tv8[8]; int tc8[8];
                #pragma unroll
                for (int k = 0; k < 8; ++k) {
                    bool r = tv16[2*k+1] < tv16[2*k];
                    tv8[k] = r ? tv16[2*k+1] : tv16[2*k];
                    tc8[k] = r ? tc16[2*k+1] : tc16[2*k];
                }
                float tv4[4]; int tc4[4];
                #pragma unroll
                for (int k = 0; k < 4; ++k) {
                    bool r = tv8[2*k+1] < tv8[2*k];
                    tv4[k] = r ? tv8[2*k+1] : tv8[2*k];
                    tc4[k] = r ? tc8[2*k+1] : tc8[2*k];
                }
                float tv2[2]; int tc2[2];
                #pragma unroll
                for (int k = 0; k < 2; ++k) {
                    bool r = tv4[2*k+1] < tv4[2*k];
                    tv2[k] = r ? tv4[2*k+1] : tv4[2*k];
                    tc2[k] = r ? tc4[2*k+1] : tc4[2*k];
                }
                bool rr = tv2[1] < tv2[0];
                float fv = rr ? tv2[1] : tv2[0];
                int   fc = rr ? tc2[1] : tc2[0];
                if (fv < FINF) {
                    double ka = (double)fv - u_i0;   // v==0 exactly for A-cols
                    if (ka < kc || (ka == kc && fc < cc)) { kc = ka; cc = fc; }
                }
            }

            // ---- combine & reduce ----
            double delta; int dc;
            const bool needReduce = (S_len > 0) || !listHit;
            if (needReduce) {
                reduce64(kc, cc);
                if (listHit) {
                    double ka = (double)vA - u_i0;
                    if (kc < ka || (kc == ka && cc < cA)) { delta = kc; dc = cc; }
                    else                                  { delta = ka; dc = cA; }
                } else { delta = kc; dc = cc; }
            } else { delta = (double)vA - u_i0; dc = cA; }

            const int pr = p0[dc];
            if (lane == 0) { cLog[K] = dc; dLog[K] = delta; }
            ++K;

            if (pr == 0) {
                // ---- augment + chronological replay of deferred updates ----
                if (lane == 0) p0[dc] = (unsigned short)i;
                __syncthreads();
                for (int m = lane; m < K - 1; m += 64) {
                    int c = cLog[m];
                    int slot = sIdx[c];
                    int r = p0[c];
                    double svv = Sv[slot], uu = u_s[r];
                    for (int t = m + 1; t < K; ++t) {
                        double d = dLog[t];
                        svv -= d; uu += d;
                    }
                    Sv[slot] = svv; u_s[r] = uu;
                }
                if (lane == 0) {
                    double uu = u_s[i];
                    for (int t = 0; t < K; ++t) uu += dLog[t];
                    u_s[i] = uu;
                }
                __syncthreads();
                break;
            }

            // ---- continue chain: append to S if new, mark slot used ----
            const bool inS = (tb[dc >> 5] >> (dc & 31)) & 1u;
            if (!inS) {
                int slot = S_len;
                if (lane == 0) {
                    ScolL[slot] = (unsigned short)dc;
                    Sv[slot]    = 0.0;
                    sIdx[dc]    = (unsigned short)slot;
                    tb[dc >> 5]       |= 1u << (dc & 31);
                    usedBits[slot >> 5] |= 1u << (slot & 31);
                }
                if (lane == (dc >> 5)) excl |= 1u << (dc & 31);
                ++S_len;
            } else {
                int slot = sIdx[dc];
                if (lane == 0) usedBits[slot >> 5] |= 1u << (slot & 31);
            }
            i0 = pr;
            u_i0 = u_s[pr];
        }
    }

    for (int c = lane; c < QQ; c += 64) {
        int pr = p0[c];
        out_inds[(size_t)b * QQ + c] = (pr > 0) ? (float)(pr - 1) : 0.0f;
        out_mask[(size_t)b * QQ + c] = (pr > 0) ? 1.0f : 0.0f;
    }
}

extern "C" void kernel_launch(void* const* d_in, const int* in_sizes, int n_in,
                              void* d_out, int out_size, void* d_ws, size_t ws_size,
                              hipStream_t stream) {
    const float* sem     = (const float*)d_in[0];
    const float* center  = (const float*)d_in[1];
    const float* size_   = (const float*)d_in[2];
    const float* gious   = (const float*)d_in[3];
    const int*   labels  = (const int*)d_in[4];
    const int*   nactual = (const int*)d_in[5];

    float* out        = (float*)d_out;
    float* out_inds   = out;
    float* out_mask   = out + BB * QQ;
    float* final_cost = out + 2 * BB * QQ;

    const size_t t_bytes = (size_t)BB * GG * QQ * sizeof(float);                 // 8 MB
    const size_t k_bytes = (size_t)BB * GG * TK * (sizeof(float) + sizeof(int)); // 256 KB
    const int use_t = (ws_size >= t_bytes) ? 1 : 0;
    const int use_k = (ws_size >= t_bytes + k_bytes) ? 1 : 0;
    float* costT = use_t ? (float*)d_ws : nullptr;
    float* topv  = (float*)((char*)d_ws + t_bytes);
    int*   topc  = (int*)((char*)d_ws + t_bytes + (size_t)BB * GG * TK * sizeof(float));

    cost_kernel<<<BB * 64, 256, 0, stream>>>(
        sem, center, size_, gious, labels, final_cost, costT, use_t);

    if (use_t) {
        if (use_k) topk_kernel<<<BB * GG, 256, 0, stream>>>(costT, topv, topc);
        hungarian_kernel<true><<<BB, 64, 0, stream>>>(
            costT, nactual, out_inds, out_mask,
            use_k ? topv : nullptr, use_k ? topc : nullptr);
    } else {
        hungarian_kernel<false><<<BB, 64, 0, stream>>>(
            final_cost, nactual, out_inds, out_mask, nullptr, nullptr);
    }
}